// Round 7
// baseline (1983.109 us; speedup 1.0000x reference)
//
#include <hip/hip_runtime.h>
#include <math.h>

#define NB 256
#define NH 2048
#define ND 8
#define NI 16
#define NT 128
#define NO 4
#define KK2 33           // K chunks of 64: 32 rec + 1 (in + pad) -> K = 2112
#define NTHR 1024

typedef __attribute__((ext_vector_type(4))) int i32x4;
typedef __attribute__((ext_vector_type(2))) long i64x2;
typedef __attribute__((ext_vector_type(2))) unsigned u32x2;

// ---- ws byte offsets ----
// W3: 3 i8 splits x [128 h16][33 kk][64 lane][16] (fragment-linear)
#define SSTR     (128u*KK2*1024u)                   // one split = 4,325,376 B
#define OFF_W3   0u
#define SZ_W3    (3u*SSTR)                          // 12,976,128
#define OFF_SC   (OFF_W3 + SZ_W3)                   // inv_scale f32[2048]
#define OFF_SCF  (OFF_SC + 8192u)                   // scale     f32[2048]
#define ZBUF_B   (16u*KK2*1024u)                    // 540,672 B per z buffer
#define OFF_ZB   (OFF_SCF + 8192u)                  // 2 x Z[16 b16][33 kk][64 lane][16] i8
#define SZ_ZB    (2u*ZBUF_B)
#define OFF_XS   (OFF_ZB + SZ_ZB)                   // [NT][NB][NI] i8 encoder spikes
#define SZ_XS    ((unsigned)NT*NB*NI)
#define OFF_V    (OFF_XS + SZ_XS)                   // [NB][NH] f32
#define SZ_V     ((unsigned)NB*NH*4u)
#define OFF_I    (OFF_V + SZ_V)
#define OFF_PIO  (OFF_I + SZ_V)                     // 2 x [NB][64][NO] f32
#define SZ_PIO   (2u*NB*64u*NO*4u)
#define OFF_VIO  (OFF_PIO + SZ_PIO)                 // vo[1024], io[1024], mx[1024]

// per-row scales: s = 22 - exp(rowmax) -> |w*2^s| < 2^23, 3 signed bytes exact
__global__ __launch_bounds__(512) void k_scale(const float* __restrict__ w_rec,
                                               const float* __restrict__ w_in,
                                               char* __restrict__ wsb) {
    const int gt = blockIdx.x * 512 + threadIdx.x;   // 256 blocks -> 2048 waves
    const int h = gt >> 6, lane = gt & 63;
    float m = 0.0f;
    for (int k = lane; k < NH; k += 64) m = fmaxf(m, fabsf(w_rec[h * NH + k]));
    if (lane < 16) m = fmaxf(m, fabsf(w_in[h * NI + lane]));
    #pragma unroll
    for (int d = 1; d < 64; d <<= 1) m = fmaxf(m, __shfl_xor(m, d, 64));
    if (lane == 0) {
        int e;
        frexpf(m, &e);           // m = f*2^e, f in [0.5,1)
        int s = 22 - e;
        ((float*)(wsb + OFF_SCF))[h] = ldexpf(1.0f, s);
        ((float*)(wsb + OFF_SC))[h]  = ldexpf(1.0f, -s);
    }
}

// quantize + split into 3 i8 planes, fragment-linear
__global__ __launch_bounds__(192) void k_pack(const float* __restrict__ w_rec,
                                              const float* __restrict__ w_in,
                                              char* __restrict__ wsb) {
    const int h = blockIdx.x, c = threadIdx.x;       // 2048 blocks, 132 chunks of 16 k
    if (c >= 132) return;
    const float scale = ((const float*)(wsb + OFF_SCF))[h];
    const int k0 = c * 16;
    const int kk = k0 >> 6, q = (k0 >> 4) & 3;
    unsigned pk[3][4] = {{0u,0u,0u,0u},{0u,0u,0u,0u},{0u,0u,0u,0u}};
    #pragma unroll
    for (int u = 0; u < 16; ++u) {
        int k = k0 + u;
        float wv = 0.0f;
        if (k < NH) wv = w_rec[h * NH + k];
        else if (k < NH + NI) wv = w_in[h * NI + (k - NH)];
        int wq = __float2int_rn(wv * scale);
        int b0_ = (wq << 24) >> 24;  int r = (wq - b0_) >> 8;
        int b1_ = (r << 24) >> 24;   int b2_ = (r - b1_) >> 8;
        int bs[3] = {b0_, b1_, b2_};
        #pragma unroll
        for (int sp = 0; sp < 3; ++sp)
            pk[sp][u >> 2] |= ((unsigned)(unsigned char)bs[sp]) << ((u & 3) * 8);
    }
    char* w3 = wsb + OFF_W3;
    unsigned base = (((unsigned)(h >> 4)) * KK2 + (unsigned)kk) * 1024u
                  + ((unsigned)q * 16u + (unsigned)(h & 15)) * 16u;
    #pragma unroll
    for (int sp = 0; sp < 3; ++sp)
        *(i32x4*)(w3 + (unsigned)sp * SSTR + base) = *(const i32x4*)pk[sp];
}

__global__ __launch_bounds__(256) void k_init(const float* __restrict__ x,
                                              char* __restrict__ wsb) {
    const int g = blockIdx.x * 256 + threadIdx.x;   // 65536 threads
    unsigned* zb32 = (unsigned*)(wsb + OFF_ZB);
    float* vst = (float*)(wsb + OFF_V);
    float* ist = (float*)(wsb + OFF_I);
    float* vio = (float*)(wsb + OFF_VIO);
    char* xsp = (char*)(wsb + OFF_XS);

    #pragma unroll
    for (int r = 0; r < 5; ++r) {
        unsigned off = (unsigned)g + (unsigned)r * 65536u;
        if (off < (SZ_ZB / 4u)) zb32[off] = 0u;
    }
    #pragma unroll
    for (int r = 0; r < 8; ++r) vst[g + r * 65536] = 0.0f;
    #pragma unroll
    for (int r = 0; r < 8; ++r) ist[g + r * 65536] = 0.0f;
    if (g < 3072) vio[g] = (g < 2048) ? 0.0f : -3.0e38f;

    if (g < NB * NI) {   // encoder cell (b, ci)
        const int b = g >> 4, ci = g & 15;
        float xv = x[b * ND + (ci & 7)];
        float c = (ci < 8) ? __fmul_rn(50.0f, xv) : __fmul_rn(-50.0f, xv);
        c = fmaxf(c, 0.0f);
        float ev = 0.0f;
        for (int t = 0; t < NT; ++t) {
            ev = __fadd_rn(ev, __fmul_rn(0.1f, __fsub_rn(c, ev)));
            float z = (__fsub_rn(ev, 1.0f) > 0.0f) ? 1.0f : 0.0f;
            xsp[t * (NB * NI) + g] = (z > 0.0f) ? (char)1 : (char)0;
            ev = (z > 0.0f) ? 0.0f : ev;
        }
    }
}

// xs[0] -> Z buffer 0 extension chunk (kk=32, k_in 0..15)
__global__ __launch_bounds__(256) void k_init2(char* __restrict__ wsb) {
    const int b = threadIdx.x;                       // 256 threads
    char* zb0 = wsb + OFF_ZB;
    const char* xsp = wsb + OFF_XS;
    i32x4 xv = *(const i32x4*)(xsp + b * 16);
    unsigned dst = (((unsigned)(b >> 4)) * KK2 + 32u) * 1024u + (unsigned)(b & 15) * 16u;
    *(i32x4*)(zb0 + dst) = xv;
}

__global__ __launch_bounds__(NTHR, 4) void k_step(const float* __restrict__ w_out,
                                                  char* __restrict__ wsb, int t) {
    __shared__ float red[4 * 64 * 34];   // 4 k-partial buffers (two-phase reduce)
    __shared__ float z_s[64 * 34];
    __shared__ float w_out_lds[128];

    const int tid = threadIdx.x;
    const int beta = blockIdx.x;
    const int xcd = beta & 7, jb = beta >> 3;
    const int ht = xcd * 8 + (jb & 7);   // 0..63 (h-tile, XCD-contiguous weights)
    const int bt = jb >> 3;              // 0..3
    const int b0 = bt * 64, h0 = ht * 32;

    const char* w3 = wsb + OFF_W3;
    const float* inv_scale = (const float*)(wsb + OFF_SC);
    char* zb = wsb + OFF_ZB;
    const char* xsp = wsb + OFF_XS;
    float* vst = (float*)(wsb + OFF_V);
    float* ist = (float*)(wsb + OFF_I);
    float* pio = (float*)(wsb + OFF_PIO);
    float* vio = (float*)(wsb + OFF_VIO);

    const char* zr = zb + (t & 1) * ZBUF_B;
    char* zw = zb + ((t + 1) & 1) * ZBUF_B;

    // LI readout update for step t-1 (block 0 owns all 1024 (b,o) cells)
    if (t > 0 && beta == 0) {
        const float* pr = pio + ((t - 1) & 1) * (NB * 64 * NO);
        const int b = tid >> 2, o = tid & 3;
        float s = 0.0f;
        #pragma unroll
        for (int jj = 0; jj < 64; ++jj) s += pr[(b * 64 + jj) * NO + o];
        float vo = vio[tid], io = vio[1024 + tid], mx = vio[2048 + tid];
        float von = __fadd_rn(vo, __fmul_rn(0.1f, __fsub_rn(io, vo)));  // old io
        io = __fadd_rn(__fmul_rn(io, 0.8f), s);
        vio[tid] = von; vio[1024 + tid] = io; vio[2048 + tid] = fmaxf(mx, von);
    }

    // xs[t+1] -> next Z extension (kk=32)
    if (ht == 0 && t + 1 < NT && tid < 64) {
        int bg = b0 + tid;
        i32x4 xv = *(const i32x4*)(xsp + ((t + 1) * NB + bg) * 16);
        unsigned dst = (((unsigned)(bg >> 4)) * KK2 + 32u) * 1024u
                     + (unsigned)(bg & 15) * 16u;
        *(i32x4*)(zw + dst) = xv;
    }
    if (tid < 128) w_out_lds[tid] = w_out[(tid >> 5) * NH + h0 + (tid & 31)];

    // ---- i8 MFMA GEMM: 16 waves = 8 K-groups x 2 b-groups; 3 splits, K=64/chunk
    const int w = tid >> 6, lane = tid & 63;
    const int kw = w & 7, rbg = w >> 3;
    const unsigned h16a = (unsigned)(ht * 2);

    i32x4 acc[2][2][3];   // [rb][hb][split]
    #pragma unroll
    for (int rb = 0; rb < 2; ++rb)
        #pragma unroll
        for (int hb = 0; hb < 2; ++hb)
            #pragma unroll
            for (int sp = 0; sp < 3; ++sp) acc[rb][hb][sp] = (i32x4){0, 0, 0, 0};

    const char* zA0 = zr + ((unsigned)(bt * 4 + rbg * 2) * KK2) * 1024u
                    + (unsigned)lane * 16u;
    const char* zA1 = zA0 + (unsigned)KK2 * 1024u;
    const char* wB  = w3 + (h16a * KK2) * 1024u + (unsigned)lane * 16u;
    const unsigned hstr = (unsigned)KK2 * 1024u;

    for (int kk = kw; kk < KK2; kk += 8) {
        const unsigned o = (unsigned)kk * 1024u;
        i64x2 a0 = *(const i64x2*)(zA0 + o);
        i64x2 a1 = *(const i64x2*)(zA1 + o);
        #pragma unroll
        for (int sp = 0; sp < 3; ++sp) {
            #pragma unroll
            for (int hb = 0; hb < 2; ++hb) {
                i64x2 bfr = *(const i64x2*)(wB + (unsigned)sp * SSTR
                                               + (unsigned)hb * hstr + o);
                acc[0][hb][sp] = __builtin_amdgcn_mfma_i32_16x16x32_i8(
                    a0[0], bfr[0], acc[0][hb][sp], 0, 0, 0);
                acc[0][hb][sp] = __builtin_amdgcn_mfma_i32_16x16x32_i8(
                    a0[1], bfr[1], acc[0][hb][sp], 0, 0, 0);
                acc[1][hb][sp] = __builtin_amdgcn_mfma_i32_16x16x32_i8(
                    a1[0], bfr[0], acc[1][hb][sp], 0, 0, 0);
                acc[1][hb][sp] = __builtin_amdgcn_mfma_i32_16x16x32_i8(
                    a1[1], bfr[1], acc[1][hb][sp], 0, 0, 0);
            }
        }
    }

    // combine splits -> f32, two-phase cross-wave reduce
    const int lk = lane >> 4, lh = lane & 15;
    const float inv0 = inv_scale[h0 + lh], inv1 = inv_scale[h0 + 16 + lh];
    float fc[2][2][4];
    #pragma unroll
    for (int rb = 0; rb < 2; ++rb)
        #pragma unroll
        for (int hb = 0; hb < 2; ++hb) {
            float invs = hb ? inv1 : inv0;
            #pragma unroll
            for (int r = 0; r < 4; ++r) {
                float f = fmaf((float)acc[rb][hb][2][r], 65536.0f,
                          fmaf((float)acc[rb][hb][1][r], 256.0f,
                               (float)acc[rb][hb][0][r]));
                fc[rb][hb][r] = f * invs;
            }
        }
    // rows: rbg*32 + rb*16 + lk*4 + r; cols: hb*16 + lh
    if (kw >= 4) {
        #pragma unroll
        for (int rb = 0; rb < 2; ++rb)
            #pragma unroll
            for (int hb = 0; hb < 2; ++hb)
                #pragma unroll
                for (int r = 0; r < 4; ++r)
                    red[(kw - 4) * 2176
                        + (rbg * 32 + rb * 16 + lk * 4 + r) * 34 + hb * 16 + lh]
                        = fc[rb][hb][r];
    }
    __syncthreads();
    if (kw < 4) {
        #pragma unroll
        for (int rb = 0; rb < 2; ++rb)
            #pragma unroll
            for (int hb = 0; hb < 2; ++hb)
                #pragma unroll
                for (int r = 0; r < 4; ++r) {
                    int ro = kw * 2176
                           + (rbg * 32 + rb * 16 + lk * 4 + r) * 34 + hb * 16 + lh;
                    red[ro] = fc[rb][hb][r] + red[ro];
                }
    }
    __syncthreads();

    // reduce 4 buffers + LIF update (2 elems/thread)
    #pragma unroll
    for (int e = 0; e < 2; ++e) {
        int idx = e * NTHR + tid;
        int bl = idx >> 5, hl = idx & 31;
        int ro = bl * 34 + hl;
        float accv = ((red[ro] + red[2176 + ro]) + red[2 * 2176 + ro]) + red[3 * 2176 + ro];
        int gidx = (b0 + bl) * NH + h0 + hl;
        float vv = vst[gidx], ii = ist[gidx];
        float vd = __fadd_rn(vv, __fmul_rn(0.1f, __fsub_rn(ii, vv)));
        float zn = (__fsub_rn(vd, 1.0f) > 0.0f) ? 1.0f : 0.0f;
        vst[gidx] = (zn > 0.0f) ? 0.0f : vd;
        ist[gidx] = __fadd_rn(__fmul_rn(ii, 0.8f), accv);
        z_s[ro] = zn;
    }
    __syncthreads();

    if (tid < 256) {
        // spikes -> Z (i8, fragment-linear; this block owns chunk kk=ht>>1)
        int b = tid >> 2, c = tid & 3;
        int bg = b0 + b;
        unsigned lo_u = 0, hi_u = 0;
        #pragma unroll
        for (int jj = 0; jj < 4; ++jj)
            lo_u |= (z_s[b * 34 + c * 8 + jj] > 0.5f ? 1u : 0u) << (jj * 8);
        #pragma unroll
        for (int jj = 0; jj < 4; ++jj)
            hi_u |= (z_s[b * 34 + c * 8 + 4 + jj] > 0.5f ? 1u : 0u) << (jj * 8);
        unsigned q = (unsigned)((ht & 1) * 2 + (c >> 1));
        unsigned dst = (((unsigned)(bg >> 4)) * KK2 + (unsigned)(ht >> 1)) * 1024u
                     + (q * 16u + (unsigned)(bg & 15)) * 16u + (unsigned)((c & 1) * 8);
        *(u32x2*)(zw + dst) = (u32x2){lo_u, hi_u};

        // readout partial: sum over this block's 32 h per (b, o)
        int o = tid & 3;
        float s = 0.0f;
        #pragma unroll
        for (int h = 0; h < 32; ++h)
            s = fmaf(z_s[b * 34 + h], w_out_lds[o * 32 + h], s);
        float* pw = pio + (t & 1) * (NB * 64 * NO);
        pw[((b0 + b) * 64 + ht) * NO + o] = s;
    }
}

__global__ __launch_bounds__(256) void k_final(char* __restrict__ wsb,
                                               float* __restrict__ out) {
    const int g = blockIdx.x * 256 + threadIdx.x;   // 1024 threads
    if (g >= NB * NO) return;
    float* vio = (float*)(wsb + OFF_VIO);
    float vo = vio[g], io = vio[1024 + g], mx = vio[2048 + g];
    float von = __fadd_rn(vo, __fmul_rn(0.1f, __fsub_rn(io, vo)));
    mx = fmaxf(mx, von);

    float mm = fmaxf(mx, __shfl_xor(mx, 1, 64));
    mm = fmaxf(mm, __shfl_xor(mm, 2, 64));
    float e = expf(__fsub_rn(mx, mm));
    float es = e;
    es += __shfl_xor(es, 1, 64);
    es += __shfl_xor(es, 2, 64);
    out[g] = e / es;
}

extern "C" void kernel_launch(void* const* d_in, const int* in_sizes, int n_in,
                              void* d_out, int out_size, void* d_ws, size_t ws_size,
                              hipStream_t stream) {
    const float* x     = (const float*)d_in[0];
    const float* w_in  = (const float*)d_in[1];
    const float* w_rec = (const float*)d_in[2];
    const float* w_out = (const float*)d_in[3];
    float* out = (float*)d_out;
    char* wsb  = (char*)d_ws;

    k_scale<<<256, 512, 0, stream>>>(w_rec, w_in, wsb);
    k_pack<<<NH, 192, 0, stream>>>(w_rec, w_in, wsb);
    k_init<<<256, 256, 0, stream>>>(x, wsb);
    k_init2<<<1, 256, 0, stream>>>(wsb);
    for (int t = 0; t < NT; ++t)
        k_step<<<256, NTHR, 0, stream>>>(w_out, wsb, t);
    k_final<<<4, 256, 0, stream>>>(wsb, out);
}

// Round 9
// 1848.884 us; speedup vs baseline: 1.0726x; 1.0726x over previous
//
#include <hip/hip_runtime.h>
#include <math.h>

#define NB 256
#define NH 2048
#define ND 8
#define NI 16
#define NT 128
#define NO 4
#define KK 32            // K chunks of 64 -> K = 2048 (rec only)
#define NTHR 512

typedef __attribute__((ext_vector_type(4))) int i32x4;
typedef __attribute__((ext_vector_type(2))) long i64x2;
typedef __attribute__((ext_vector_type(2))) unsigned u32x2;

// ---- ws byte offsets ----
// W4: 4 i8 splits x [128 h16][32 kk][64 lane][16] (fragment-linear)
#define SSTR     (128u*KK*1024u)                    // one split = 4,194,304 B
#define OFF_W4   0u
#define SZ_W4    (4u*SSTR)                          // 16,777,216
#define OFF_SC   (OFF_W4 + SZ_W4)                   // inv_scale f32[2048]
#define OFF_SCF  (OFF_SC + 8192u)                   // scale     f32[2048]
#define ZBUF_B   (16u*KK*1024u)                     // 524,288 B per z buffer
#define OFF_ZB   (OFF_SCF + 8192u)                  // 2 x Z[16 b16][32 kk][64 lane][16] i8
#define SZ_ZB    (2u*ZBUF_B)
#define OFF_XS   (OFF_ZB + SZ_ZB)                   // [NT][NB][NI] i8 encoder spikes
#define SZ_XS    ((unsigned)NT*NB*NI)
#define OFF_V    (OFF_XS + SZ_XS)                   // [NB][NH] f32
#define SZ_V     ((unsigned)NB*NH*4u)
#define OFF_I    (OFF_V + SZ_V)
#define OFF_PIO  (OFF_I + SZ_V)                     // 2 x [NB][64][NO] f32
#define SZ_PIO   (2u*NB*64u*NO*4u)
#define OFF_VIO  (OFF_PIO + SZ_PIO)                 // vo[1024], io[1024], mx[1024]

// per-row scales over w_rec: s = 30 - exp(rowmax) -> |w*2^s| < 2^30, 4 signed bytes exact
__global__ __launch_bounds__(512) void k_scale(const float* __restrict__ w_rec,
                                               char* __restrict__ wsb) {
    const int gt = blockIdx.x * 512 + threadIdx.x;   // 256 blocks -> 2048 waves
    const int h = gt >> 6, lane = gt & 63;
    float m = 0.0f;
    for (int k = lane; k < NH; k += 64) m = fmaxf(m, fabsf(w_rec[h * NH + k]));
    #pragma unroll
    for (int d = 1; d < 64; d <<= 1) m = fmaxf(m, __shfl_xor(m, d, 64));
    if (lane == 0) {
        int e;
        frexpf(m, &e);           // m = f*2^e, f in [0.5,1)
        int s = 30 - e;
        ((float*)(wsb + OFF_SCF))[h] = ldexpf(1.0f, s);
        ((float*)(wsb + OFF_SC))[h]  = ldexpf(1.0f, -s);
    }
}

// quantize + split into 4 i8 planes, fragment-linear (16 consecutive k per lane entry)
__global__ __launch_bounds__(128) void k_pack(const float* __restrict__ w_rec,
                                              char* __restrict__ wsb) {
    const int h = blockIdx.x, c = threadIdx.x;       // 2048 blocks, 128 chunks of 16 k
    const float scale = ((const float*)(wsb + OFF_SCF))[h];
    const int k0 = c * 16;
    const int kk = k0 >> 6, q = (k0 >> 4) & 3;
    unsigned pk[4][4] = {{0u,0u,0u,0u},{0u,0u,0u,0u},{0u,0u,0u,0u},{0u,0u,0u,0u}};
    #pragma unroll
    for (int u = 0; u < 16; ++u) {
        float wv = w_rec[h * NH + k0 + u];
        int wq = __float2int_rn(wv * scale);
        int b0_ = (wq << 24) >> 24;  int r = (wq - b0_) >> 8;
        int b1_ = (r << 24) >> 24;   r = (r - b1_) >> 8;
        int b2_ = (r << 24) >> 24;   int b3_ = (r - b2_) >> 8;
        int bs[4] = {b0_, b1_, b2_, b3_};
        #pragma unroll
        for (int sp = 0; sp < 4; ++sp)
            pk[sp][u >> 2] |= ((unsigned)(unsigned char)bs[sp]) << ((u & 3) * 8);
    }
    char* w4 = wsb + OFF_W4;
    unsigned base = (((unsigned)(h >> 4)) * KK + (unsigned)kk) * 1024u
                  + ((unsigned)q * 16u + (unsigned)(h & 15)) * 16u;
    #pragma unroll
    for (int sp = 0; sp < 4; ++sp)
        *(i32x4*)(w4 + (unsigned)sp * SSTR + base) = *(const i32x4*)pk[sp];
}

__global__ __launch_bounds__(256) void k_init(const float* __restrict__ x,
                                              char* __restrict__ wsb) {
    const int g = blockIdx.x * 256 + threadIdx.x;   // 65536 threads
    unsigned* zb32 = (unsigned*)(wsb + OFF_ZB);     // 262,144 uints
    float* vst = (float*)(wsb + OFF_V);
    float* ist = (float*)(wsb + OFF_I);
    float* vio = (float*)(wsb + OFF_VIO);
    char* xsp = (char*)(wsb + OFF_XS);

    #pragma unroll
    for (int r = 0; r < 4; ++r) zb32[g + r * 65536] = 0u;
    #pragma unroll
    for (int r = 0; r < 8; ++r) vst[g + r * 65536] = 0.0f;
    #pragma unroll
    for (int r = 0; r < 8; ++r) ist[g + r * 65536] = 0.0f;
    if (g < 3072) vio[g] = (g < 2048) ? 0.0f : -3.0e38f;

    if (g < NB * NI) {   // encoder cell (b, ci)
        const int b = g >> 4, ci = g & 15;
        float xv = x[b * ND + (ci & 7)];
        float c = (ci < 8) ? __fmul_rn(50.0f, xv) : __fmul_rn(-50.0f, xv);
        c = fmaxf(c, 0.0f);
        float ev = 0.0f;
        for (int t = 0; t < NT; ++t) {
            ev = __fadd_rn(ev, __fmul_rn(0.1f, __fsub_rn(c, ev)));
            float z = (__fsub_rn(ev, 1.0f) > 0.0f) ? 1.0f : 0.0f;
            xsp[t * (NB * NI) + g] = (z > 0.0f) ? (char)1 : (char)0;
            ev = (z > 0.0f) ? 0.0f : ev;
        }
    }
}

__global__ __launch_bounds__(NTHR, 2) void k_step(const float* __restrict__ w_in,
                                                  const float* __restrict__ w_out,
                                                  char* __restrict__ wsb, int t) {
    __shared__ float red[4 * 64 * 34];   // 4 k-partial buffers (two-phase reduce)
    __shared__ float z_s[64 * 34];
    __shared__ float xs_f[64 * 17];      // this step's encoder spikes (f32)
    __shared__ float w_in_lds[32 * 17];  // w_in tile (f32)
    __shared__ float w_out_lds[128];

    const int tid = threadIdx.x;
    const int beta = blockIdx.x;
    const int xcd = beta & 7, jb = beta >> 3;
    const int ht = xcd * 8 + (jb & 7);   // 0..63 (h-tile, XCD-contiguous weights)
    const int bt = jb >> 3;              // 0..3
    const int b0 = bt * 64, h0 = ht * 32;

    const char* w4 = wsb + OFF_W4;
    const float* inv_scale = (const float*)(wsb + OFF_SC);
    char* zb = wsb + OFF_ZB;
    const char* xsp = wsb + OFF_XS;
    float* vst = (float*)(wsb + OFF_V);
    float* ist = (float*)(wsb + OFF_I);
    float* pio = (float*)(wsb + OFF_PIO);
    float* vio = (float*)(wsb + OFF_VIO);

    const char* zr = zb + (t & 1) * ZBUF_B;
    char* zw = zb + ((t + 1) & 1) * ZBUF_B;

    // LI readout update for step t-1 (stream-ordered; blocks 0-1 cover all 1024 cells)
    const int g = beta * NTHR + tid;
    if (t > 0 && g < NB * NO) {
        const float* pr = pio + ((t - 1) & 1) * (NB * 64 * NO);
        const int b = g >> 2, o = g & 3;
        float s = 0.0f;
        #pragma unroll
        for (int jj = 0; jj < 64; ++jj) s += pr[(b * 64 + jj) * NO + o];
        float vo = vio[g], io = vio[1024 + g], mx = vio[2048 + g];
        float von = __fadd_rn(vo, __fmul_rn(0.1f, __fsub_rn(io, vo)));  // old io
        io = __fadd_rn(__fmul_rn(io, 0.8f), s);
        vio[g] = von; vio[1024 + g] = io; vio[2048 + g] = fmaxf(mx, von);
    }

    // stage xs[t] (as f32), w_in tile, w_out tile
    #pragma unroll
    for (int r = 0; r < 2; ++r) {
        int v = tid + r * NTHR;          // 0..1023
        int bl = v >> 4, ci = v & 15;
        xs_f[bl * 17 + ci] = (float)xsp[t * (NB * NI) + (b0 + bl) * NI + ci];
    }
    {
        int hl = tid >> 4, i2 = tid & 15;   // 512 = 32 x 16
        w_in_lds[hl * 17 + i2] = w_in[(h0 + hl) * NI + i2];
    }
    if (tid < 128) w_out_lds[tid] = w_out[(tid >> 5) * NH + h0 + (tid & 31)];

    // ---- i8 MFMA GEMM: 8 waves, contiguous 4 K-chunks each, double-buffered loads
    const int w = tid >> 6, lane = tid & 63;
    const unsigned h16a = (unsigned)(ht * 2);
    const unsigned lb = (unsigned)lane * 16u;
    const unsigned kk0 = (unsigned)(w * 4);

    i32x4 acc[4][2][4];   // [rb][hb][split]
    #pragma unroll
    for (int rb = 0; rb < 4; ++rb)
        #pragma unroll
        for (int hb = 0; hb < 2; ++hb)
            #pragma unroll
            for (int sp = 0; sp < 4; ++sp) acc[rb][hb][sp] = (i32x4){0, 0, 0, 0};

    const char* zA = zr + (((unsigned)(bt * 4) * KK + kk0) * 1024u) + lb;  // rb stride 32768
    const char* wB = w4 + ((h16a * KK + kk0) * 1024u) + lb;                // hb stride 32768

    i64x2 a[2][4], bv[2][2][4];
    #pragma unroll
    for (int rb = 0; rb < 4; ++rb)
        a[0][rb] = *(const i64x2*)(zA + (unsigned)rb * 32768u);
    #pragma unroll
    for (int hb = 0; hb < 2; ++hb)
        #pragma unroll
        for (int sp = 0; sp < 4; ++sp)
            bv[0][hb][sp] = *(const i64x2*)(wB + (unsigned)sp * SSTR + (unsigned)hb * 32768u);

    #pragma unroll
    for (int c = 0; c < 4; ++c) {
        const int cur = c & 1, nxt = cur ^ 1;
        if (c < 3) {   // prefetch chunk c+1 while chunk c computes
            const unsigned co = (unsigned)(c + 1) * 1024u;
            #pragma unroll
            for (int rb = 0; rb < 4; ++rb)
                a[nxt][rb] = *(const i64x2*)(zA + (unsigned)rb * 32768u + co);
            #pragma unroll
            for (int hb = 0; hb < 2; ++hb)
                #pragma unroll
                for (int sp = 0; sp < 4; ++sp)
                    bv[nxt][hb][sp] = *(const i64x2*)(wB + (unsigned)sp * SSTR
                                                         + (unsigned)hb * 32768u + co);
        }
        #pragma unroll
        for (int sp = 0; sp < 4; ++sp)
            #pragma unroll
            for (int hb = 0; hb < 2; ++hb)
                #pragma unroll
                for (int rb = 0; rb < 4; ++rb) {
                    acc[rb][hb][sp] = __builtin_amdgcn_mfma_i32_16x16x32_i8(
                        a[cur][rb][0], bv[cur][hb][sp][0], acc[rb][hb][sp], 0, 0, 0);
                    acc[rb][hb][sp] = __builtin_amdgcn_mfma_i32_16x16x32_i8(
                        a[cur][rb][1], bv[cur][hb][sp][1], acc[rb][hb][sp], 0, 0, 0);
                }
    }

    // combine splits -> f32, two-phase cross-wave reduce
    const int lk = lane >> 4, lh = lane & 15;
    const float inv0 = inv_scale[h0 + lh], inv1 = inv_scale[h0 + 16 + lh];
    float fc[4][2][4];
    #pragma unroll
    for (int rb = 0; rb < 4; ++rb)
        #pragma unroll
        for (int hb = 0; hb < 2; ++hb) {
            float invs = hb ? inv1 : inv0;
            #pragma unroll
            for (int r = 0; r < 4; ++r) {
                float f = fmaf((float)acc[rb][hb][3][r], 16777216.0f,
                          fmaf((float)acc[rb][hb][2][r], 65536.0f,
                          fmaf((float)acc[rb][hb][1][r], 256.0f,
                               (float)acc[rb][hb][0][r])));
                fc[rb][hb][r] = f * invs;
            }
        }
    if (w >= 4) {
        #pragma unroll
        for (int rb = 0; rb < 4; ++rb)
            #pragma unroll
            for (int hb = 0; hb < 2; ++hb)
                #pragma unroll
                for (int r = 0; r < 4; ++r)
                    red[(w - 4) * 2176 + (rb * 16 + lk * 4 + r) * 34 + hb * 16 + lh]
                        = fc[rb][hb][r];
    }
    __syncthreads();
    if (w < 4) {
        #pragma unroll
        for (int rb = 0; rb < 4; ++rb)
            #pragma unroll
            for (int hb = 0; hb < 2; ++hb)
                #pragma unroll
                for (int r = 0; r < 4; ++r) {
                    int ro = w * 2176 + (rb * 16 + lk * 4 + r) * 34 + hb * 16 + lh;
                    red[ro] = fc[rb][hb][r] + red[ro];
                }
    }
    __syncthreads();

    // reduce 4 buffers + input current (f32) + LIF update (4 elems/thread: 2048 = 64b x 32h)
    #pragma unroll
    for (int e = 0; e < 4; ++e) {
        int idx = e * NTHR + tid;
        int bl = idx >> 5, hl = idx & 31;
        int ro = bl * 34 + hl;
        float accv = ((red[ro] + red[2176 + ro]) + red[2 * 2176 + ro]) + red[3 * 2176 + ro];
        float c = 0.0f;
        #pragma unroll
        for (int i = 0; i < NI; ++i)
            c = fmaf(xs_f[bl * 17 + i], w_in_lds[hl * 17 + i], c);
        int gidx = (b0 + bl) * NH + h0 + hl;
        float vv = vst[gidx], ii = ist[gidx];
        float vd = __fadd_rn(vv, __fmul_rn(0.1f, __fsub_rn(ii, vv)));
        float zn = (__fsub_rn(vd, 1.0f) > 0.0f) ? 1.0f : 0.0f;
        vst[gidx] = (zn > 0.0f) ? 0.0f : vd;
        ist[gidx] = __fadd_rn(__fadd_rn(__fmul_rn(ii, 0.8f), c), accv);
        z_s[ro] = zn;
    }
    __syncthreads();

    if (tid < 256) {
        // spikes -> Z (i8, fragment-linear; this block owns chunk kk=ht>>1)
        int b = tid >> 2, c = tid & 3;
        int bg = b0 + b;
        unsigned lo_u = 0, hi_u = 0;
        #pragma unroll
        for (int jj = 0; jj < 4; ++jj)
            lo_u |= (z_s[b * 34 + c * 8 + jj] > 0.5f ? 1u : 0u) << (jj * 8);
        #pragma unroll
        for (int jj = 0; jj < 4; ++jj)
            hi_u |= (z_s[b * 34 + c * 8 + 4 + jj] > 0.5f ? 1u : 0u) << (jj * 8);
        unsigned q = (unsigned)((ht & 1) * 2 + (c >> 1));
        unsigned dst = (((unsigned)(bg >> 4)) * KK + (unsigned)(ht >> 1)) * 1024u
                     + (q * 16u + (unsigned)(bg & 15)) * 16u + (unsigned)((c & 1) * 8);
        *(u32x2*)(zw + dst) = (u32x2){lo_u, hi_u};

        // readout partial: sum over this block's 32 h per (b, o)
        int o = tid & 3;
        float s = 0.0f;
        #pragma unroll
        for (int h = 0; h < 32; ++h)
            s = fmaf(z_s[b * 34 + h], w_out_lds[o * 32 + h], s);
        float* pw = pio + (t & 1) * (NB * 64 * NO);
        pw[((b0 + b) * 64 + ht) * NO + o] = s;
    }
}

__global__ __launch_bounds__(256) void k_final(char* __restrict__ wsb,
                                               float* __restrict__ out) {
    const int g = blockIdx.x * 256 + threadIdx.x;   // 1024 threads
    if (g >= NB * NO) return;
    float* vio = (float*)(wsb + OFF_VIO);
    float vo = vio[g], io = vio[1024 + g], mx = vio[2048 + g];
    float von = __fadd_rn(vo, __fmul_rn(0.1f, __fsub_rn(io, vo)));
    mx = fmaxf(mx, von);

    float mm = fmaxf(mx, __shfl_xor(mx, 1, 64));
    mm = fmaxf(mm, __shfl_xor(mm, 2, 64));
    float e = expf(__fsub_rn(mx, mm));
    float es = e;
    es += __shfl_xor(es, 1, 64);
    es += __shfl_xor(es, 2, 64);
    out[g] = e / es;
}

extern "C" void kernel_launch(void* const* d_in, const int* in_sizes, int n_in,
                              void* d_out, int out_size, void* d_ws, size_t ws_size,
                              hipStream_t stream) {
    const float* x     = (const float*)d_in[0];
    const float* w_in  = (const float*)d_in[1];
    const float* w_rec = (const float*)d_in[2];
    const float* w_out = (const float*)d_in[3];
    float* out = (float*)d_out;
    char* wsb  = (char*)d_ws;

    k_scale<<<256, 512, 0, stream>>>(w_rec, wsb);
    k_pack<<<NH, 128, 0, stream>>>(w_rec, wsb);
    k_init<<<256, 256, 0, stream>>>(x, wsb);
    for (int t = 0; t < NT; ++t)
        k_step<<<256, NTHR, 0, stream>>>(w_in, w_out, wsb, t);
    k_final<<<4, 256, 0, stream>>>(wsb, out);
}